// Round 1
// baseline (120.939 us; speedup 1.0000x reference)
//
#include <hip/hip_runtime.h>
#include <stdint.h>

// ---- AdEx constants (f32 versions of the Python f64 values) ----
#define THRC      (-50.4f)
#define ELC       (-70.6f)
#define V_RESETC  (-70.6f)
#define DT_GL_C   (0.10676156583629893f)   // DT*GL/C
#define DELTATC   (2.0f)
#define DT_C      (0.0035587188612099642f) // DT/C
#define DT_TAUW   (0.006944444444444444f)  // DT/TAUW
#define DTA_TAUW  (0.027777777777777776f)  // DT*A/TAUW
#define BCONST    (0.0805f)
#define EXPCLIP   (281.0f)                 // 30 / DT_GL__C

#define M_TOT 8192
#define N_IN  256
#define UNITS 1024
#define K_TOT 1792   // [Xhi 256 | Xlo 256 | Xhi 256 | Z 1024]
#define CH    (8192*1024)

typedef __attribute__((ext_vector_type(8))) short s16x8;
typedef __attribute__((ext_vector_type(4))) float f32x4;

__device__ __forceinline__ unsigned short f2bf(float f) {
  union { float f; unsigned int u; } v; v.f = f;
  unsigned int r = v.u + 0x7fffu + ((v.u >> 16) & 1u);  // RNE
  return (unsigned short)(r >> 16);
}
__device__ __forceinline__ float bf2f(unsigned short h) {
  union { unsigned int u; float f; } v; v.u = ((unsigned int)h) << 16; return v.f;
}

__device__ __forceinline__ void gload_lds16(const void* g, void* l) {
  __builtin_amdgcn_global_load_lds(
      (const __attribute__((address_space(1))) void*)g,
      (__attribute__((address_space(3))) void*)l, 16, 0, 0);
}

// ---- build A = [Xhi | Xlo | Xhi | Zbf16], row-major 8192 x 1792 bf16 ----
__global__ __launch_bounds__(256) void build_a(const float* __restrict__ X,
                                               const float* __restrict__ Z,
                                               unsigned short* __restrict__ A) {
  int o = blockIdx.x * 256 + threadIdx.x;       // octet index, 8192*224 total
  int row = o / 224;
  int c8 = (o - row * 224) * 8;
  const float* src; bool lo = false;
  if (c8 < 256)        { src = X + (size_t)row * 256 + c8; }
  else if (c8 < 512)   { src = X + (size_t)row * 256 + (c8 - 256); lo = true; }
  else if (c8 < 768)   { src = X + (size_t)row * 256 + (c8 - 512); }
  else                 { src = Z + (size_t)row * 1024 + (c8 - 768); }
  float4 f0 = *(const float4*)(src);
  float4 f1 = *(const float4*)(src + 4);
  float fv[8] = {f0.x, f0.y, f0.z, f0.w, f1.x, f1.y, f1.z, f1.w};
  unsigned short h[8];
#pragma unroll
  for (int i = 0; i < 8; ++i) {
    unsigned short hi = f2bf(fv[i]);
    h[i] = lo ? f2bf(fv[i] - bf2f(hi)) : hi;
  }
  uint4 pk;
  pk.x = (unsigned)h[0] | ((unsigned)h[1] << 16);
  pk.y = (unsigned)h[2] | ((unsigned)h[3] << 16);
  pk.z = (unsigned)h[4] | ((unsigned)h[5] << 16);
  pk.w = (unsigned)h[6] | ((unsigned)h[7] << 16);
  *(uint4*)(A + (size_t)row * K_TOT + c8) = pk;
}

// ---- build B^T (N-major, 1024 x 1792 bf16): [Wi_hi; Wi_hi; Wi_lo; Wr_nodiag] ----
__global__ __launch_bounds__(256) void build_b(const float* __restrict__ Wi,
                                               const float* __restrict__ Wr,
                                               unsigned short* __restrict__ BT) {
  __shared__ unsigned short tile[32][33];
  int tx = threadIdx.x & 31, ty = threadIdx.x >> 5;   // tx: n-lane, ty: k-lane
  int k0 = blockIdx.x * 32, n0 = blockIdx.y * 32;
#pragma unroll
  for (int j = 0; j < 4; ++j) {
    int kk = k0 + ty + j * 8;
    int n  = n0 + tx;
    float f; bool lo = false;
    if (kk < 256)       f = Wi[(size_t)kk * 1024 + n];
    else if (kk < 512)  f = Wi[(size_t)(kk - 256) * 1024 + n];
    else if (kk < 768) { f = Wi[(size_t)(kk - 512) * 1024 + n]; lo = true; }
    else { int kr = kk - 768; f = (kr == n) ? 0.0f : Wr[(size_t)kr * 1024 + n]; }
    unsigned short h = f2bf(f);
    if (lo) h = f2bf(f - bf2f(h));
    tile[ty + j * 8][tx] = h;
  }
  __syncthreads();
#pragma unroll
  for (int j = 0; j < 4; ++j) {
    int n  = n0 + ty + j * 8;
    int kk = k0 + tx;
    BT[(size_t)n * K_TOT + kk] = tile[tx][ty + j * 8];
  }
}

// ---- fused GEMM (i_t) + AdEx epilogue ----
// 128x128 tile, 256 threads = 4 waves (2x2), each wave 64x64 via 4x4 frags of 16x16x32.
__global__ __launch_bounds__(256) void adex_gemm(
    const unsigned short* __restrict__ A, const unsigned short* __restrict__ BT,
    const float* __restrict__ oV, const int* __restrict__ oR,
    const float* __restrict__ oW, const float* __restrict__ oZ,
    float* __restrict__ out)
{
  __shared__ unsigned short As[128 * 32];
  __shared__ unsigned short Bs[128 * 32];
  const int tid  = threadIdx.x;
  const int wid  = tid >> 6;
  const int lane = tid & 63;
  const int rowA0 = blockIdx.x * 128;   // M tile (64 tiles)
  const int colB0 = blockIdx.y * 128;   // N tile (8 tiles)

  f32x4 acc[4][4];
#pragma unroll
  for (int i = 0; i < 4; ++i)
#pragma unroll
    for (int j = 0; j < 4; ++j) acc[i][j] = (f32x4){0.f, 0.f, 0.f, 0.f};

  const int ar = tid >> 2;          // 0..63
  const int ac = (tid & 3) * 8;     // 0,8,16,24
  const unsigned short* aSrc0 = A  + (size_t)(rowA0 + ar)      * K_TOT + ac;
  const unsigned short* aSrc1 = A  + (size_t)(rowA0 + 64 + ar) * K_TOT + ac;
  const unsigned short* bSrc0 = BT + (size_t)(colB0 + ar)      * K_TOT + ac;
  const unsigned short* bSrc1 = BT + (size_t)(colB0 + 64 + ar) * K_TOT + ac;
  unsigned short* aDst0 = As + tid * 8;          // linear: wave-uniform base + lane*16B
  unsigned short* aDst1 = As + 2048 + tid * 8;
  unsigned short* bDst0 = Bs + tid * 8;
  unsigned short* bDst1 = Bs + 2048 + tid * 8;

  const int wr  = (wid >> 1) * 64, wc = (wid & 1) * 64;
  const int l15 = lane & 15, l4 = lane >> 4;

  for (int ks = 0; ks < K_TOT / 32; ++ks) {
    gload_lds16(aSrc0, aDst0);
    gload_lds16(aSrc1, aDst1);
    gload_lds16(bSrc0, bDst0);
    gload_lds16(bSrc1, bDst1);
    aSrc0 += 32; aSrc1 += 32; bSrc0 += 32; bSrc1 += 32;
    asm volatile("s_waitcnt vmcnt(0)" ::: "memory");
    __syncthreads();

    s16x8 af[4], bfv[4];
#pragma unroll
    for (int f = 0; f < 4; ++f)
      af[f] = *(const s16x8*)(As + (wr + f * 16 + l15) * 32 + l4 * 8);
#pragma unroll
    for (int f = 0; f < 4; ++f)
      bfv[f] = *(const s16x8*)(Bs + (wc + f * 16 + l15) * 32 + l4 * 8);
#pragma unroll
    for (int i = 0; i < 4; ++i)
#pragma unroll
      for (int j = 0; j < 4; ++j)
        acc[i][j] = __builtin_amdgcn_mfma_f32_16x16x32_bf16(af[i], bfv[j], acc[i][j], 0, 0, 0);
    __syncthreads();
  }

  // Epilogue: C/D layout col = lane&15, row = (lane>>4)*4 + reg  [m89-verified]
#pragma unroll
  for (int i = 0; i < 4; ++i) {
    int mBase = rowA0 + wr + i * 16 + l4 * 4;
#pragma unroll
    for (int j = 0; j < 4; ++j) {
      int u = colB0 + wc + j * 16 + l15;
#pragma unroll
      for (int r = 0; r < 4; ++r) {
        int m = mBase + r;
        size_t idx = (size_t)m * UNITS + u;
        float it = acc[i][j][r];
        float ov = oV[idx];
        float ow = oW[idx];
        float oz = oZ[idx];
        int   orr = oR[idx];
        float ex = expf((ov - THRC) * 0.5f);          // /DELTAT
        ex = fminf(ex, EXPCLIP);
        float nv = ov - DT_GL_C * (ov - ELC) + (DT_GL_C * DELTATC) * ex + (it - ow) * DT_C;
        nv = (oz > 0.5f) ? V_RESETC : nv;
        float nw = ow - DT_TAUW * ow + DTA_TAUW * (ov - ELC) + BCONST * oz;
        float nz = (nv > THRC) ? 1.0f : 0.0f;         // sign(v_scaled) == sign(nv-THR)
        if (orr > 0) nz = 0.0f;
        int nr = orr - 1 + (nz > 0.5f ? 5 : 0);
        nr = nr < 0 ? 0 : (nr > 5 ? 5 : nr);
        out[idx]           = nv;
        out[CH + idx]      = nz;
        out[2 * CH + idx]  = (float)nr;
        out[3 * CH + idx]  = nw;
      }
    }
  }
}

extern "C" void kernel_launch(void* const* d_in, const int* in_sizes, int n_in,
                              void* d_out, int out_size, void* d_ws, size_t ws_size,
                              hipStream_t stream) {
  const float* X  = (const float*)d_in[0];
  const float* oV = (const float*)d_in[1];
  const int*   oR = (const int*)d_in[2];
  const float* oW = (const float*)d_in[3];
  const float* oZ = (const float*)d_in[4];
  const float* Wi = (const float*)d_in[5];
  const float* Wr = (const float*)d_in[6];
  unsigned short* Aall = (unsigned short*)d_ws;                       // 8192*1792*2 = 29.36 MB
  unsigned short* BT   = Aall + (size_t)M_TOT * K_TOT;                // 1024*1792*2 =  3.67 MB
  float* out = (float*)d_out;

  hipLaunchKernelGGL(build_a, dim3((M_TOT * (K_TOT / 8)) / 256), dim3(256), 0, stream, X, oZ, Aall);
  hipLaunchKernelGGL(build_b, dim3(K_TOT / 32, UNITS / 32), dim3(256), 0, stream, Wi, Wr, BT);
  hipLaunchKernelGGL(adex_gemm, dim3(M_TOT / 128, UNITS / 128), dim3(256), 0, stream,
                     Aall, BT, oV, oR, oW, oZ, out);
}